// Round 1
// baseline (52.451 us; speedup 1.0000x reference)
//
#include <hip/hip_runtime.h>

// GaussianAntecedent: out[n,r] = mem[n,r] / (sum_r mem[n,r] + 1e-8)
// mem[n,r] = prod_d max(exp(-0.5*((x-c)/(sigma+eps))^2), 1e-8)
//          = exp2( sum_d max( (x-c)^2 * m_rd , log2(1e-8) ) ),
//   m_rd = -0.5*log2(e)/(sigma+eps)^2
//
// Layout: lane = rule (R=64 == wavefront). Per-lane constants c[32], m[32]
// in VGPRs, loaded once per wave, amortized over ROWS_PER_WAVE rows.
// X row is wave-uniform -> readfirstlane -> scalar loads (SGPR, free).
// Normalizer via __shfl_xor wave reduction. Coalesced dword stores.

constexpr int DDIM = 32;
constexpr int RRULES = 64;
constexpr int ROWS_PER_WAVE = 32;

__global__ __launch_bounds__(256) void gauss_antecedent_kernel(
    const float* __restrict__ X,
    const float* __restrict__ centers,
    const float* __restrict__ sigma,
    float* __restrict__ out,
    int N)
{
    const int lane = threadIdx.x & 63;
    const int wave_in_block = threadIdx.x >> 6;
    const int wave_id = blockIdx.x * 4 + wave_in_block;
    const int row0 = wave_id * ROWS_PER_WAVE;
    if (row0 >= N) return;

    // Per-lane (rule = lane) constants. 8KB arrays -> L1/L2 resident;
    // gather cost amortized over ROWS_PER_WAVE rows.
    float c[DDIM], m[DDIM];
    const float KNEG = -0.72134752044448170f;   // -0.5 * log2(e)
    #pragma unroll
    for (int d = 0; d < DDIM; d += 4) {
        float4 cc = *reinterpret_cast<const float4*>(&centers[lane * DDIM + d]);
        float4 ss = *reinterpret_cast<const float4*>(&sigma[lane * DDIM + d]);
        c[d + 0] = cc.x; c[d + 1] = cc.y; c[d + 2] = cc.z; c[d + 3] = cc.w;
        float s0 = ss.x + 1e-8f, s1 = ss.y + 1e-8f;
        float s2 = ss.z + 1e-8f, s3 = ss.w + 1e-8f;
        m[d + 0] = KNEG / (s0 * s0);
        m[d + 1] = KNEG / (s1 * s1);
        m[d + 2] = KNEG / (s2 * s2);
        m[d + 3] = KNEG / (s3 * s3);
    }
    const float L2CLAMP = -26.575424759098897f; // log2(1e-8)

    const int rowEnd = (row0 + ROWS_PER_WAVE < N) ? (row0 + ROWS_PER_WAVE) : N;
    for (int n = row0; n < rowEnd; ++n) {
        // n is wave-uniform by construction; force SGPR so X reads become s_load.
        const int ns = __builtin_amdgcn_readfirstlane(n);
        const float* __restrict__ xr = X + (size_t)ns * DDIM;

        float acc = 0.0f;
        #pragma unroll
        for (int d = 0; d < DDIM; ++d) {
            float dd = xr[d] - c[d];      // SGPR - VGPR
            float t  = dd * dd;
            float s  = t * m[d];
            acc += fmaxf(s, L2CLAMP);
        }
        float mem = exp2f(acc);           // one transcendental per (n, r)

        // Wave-wide sum of mem across the 64 rules.
        float S = mem;
        #pragma unroll
        for (int k = 32; k >= 1; k >>= 1)
            S += __shfl_xor(S, k, 64);

        out[(size_t)ns * RRULES + lane] = mem / (S + 1e-8f);
    }
}

extern "C" void kernel_launch(void* const* d_in, const int* in_sizes, int n_in,
                              void* d_out, int out_size, void* d_ws, size_t ws_size,
                              hipStream_t stream) {
    const float* X       = (const float*)d_in[0];
    const float* centers = (const float*)d_in[1];
    const float* sigma   = (const float*)d_in[2];
    float* out = (float*)d_out;

    const int N = in_sizes[0] / DDIM;                 // 100000
    const int rows_per_block = ROWS_PER_WAVE * 4;     // 4 waves of 64
    const int grid = (N + rows_per_block - 1) / rows_per_block;

    gauss_antecedent_kernel<<<grid, 256, 0, stream>>>(X, centers, sigma, out, N);
}

// Round 2
// 47.284 us; speedup vs baseline: 1.1093x; 1.1093x over previous
//
#include <hip/hip_runtime.h>

// GaussianAntecedent: out[n,r] = mem[n,r] / (sum_r mem[n,r] + 1e-8)
// mem[n,r] = prod_d max(exp(-0.5*((x-c)/(sigma+eps))^2), 1e-8)
//          = exp2( -sum_d min( (q_rd*x + pn_rd)^2 , -L ) )
//   q_rd  = sqrt(0.5*log2 e)/(sigma+eps),  pn_rd = -c*q_rd,  L = log2(1e-8)
//
// lane = rule (R=64 == wavefront). Per-lane constants q[32], pn[32] in VGPRs.
// Inner loop as float2 pairs -> v_pk_fma/v_pk_mul/v_pk_add candidates.
// 4 independent accumulators (chain length 4). X row loaded as broadcast
// float4 VMEM (same addr all lanes -> 1 L1 transaction, data lands in VGPR
// pairs ready for packed ops). ROWS_PER_WAVE=16 -> 6250 waves for occupancy.

typedef float v2f __attribute__((ext_vector_type(2)));

constexpr int DDIM = 32;
constexpr int RR   = 64;
constexpr int ROWS_PER_WAVE = 16;
constexpr int WPB  = 4;   // waves per block (256 threads)

__device__ inline float fast_exp2(float x) {
#if __has_builtin(__builtin_amdgcn_exp2f)
    return __builtin_amdgcn_exp2f(x);
#else
    return exp2f(x);
#endif
}

__global__ __launch_bounds__(256, 4) void gauss_antecedent_kernel(
    const float* __restrict__ X,
    const float* __restrict__ centers,
    const float* __restrict__ sigma,
    float* __restrict__ out, int N)
{
    const int lane = threadIdx.x & 63;
    const int wid  = blockIdx.x * WPB + (threadIdx.x >> 6);
    const int row0 = wid * ROWS_PER_WAVE;
    if (row0 >= N) return;

    const float SQK  = 0.84932180028801907f;  // sqrt(0.5 * log2(e))
    const float NEGL = 26.575424759098897f;   // -log2(1e-8)

    // Per-lane (rule = lane) constants, held in VGPR pairs.
    v2f q2[DDIM / 2], pn2[DDIM / 2];
    #pragma unroll
    for (int d = 0; d < DDIM; d += 4) {
        float4 cc = *reinterpret_cast<const float4*>(&centers[lane * DDIM + d]);
        float4 ss = *reinterpret_cast<const float4*>(&sigma[lane * DDIM + d]);
        float qa = SQK / (ss.x + 1e-8f);
        float qb = SQK / (ss.y + 1e-8f);
        float qc = SQK / (ss.z + 1e-8f);
        float qd = SQK / (ss.w + 1e-8f);
        q2[d / 2 + 0] = (v2f){qa, qb};
        q2[d / 2 + 1] = (v2f){qc, qd};
        pn2[d / 2 + 0] = (v2f){-cc.x * qa, -cc.y * qb};
        pn2[d / 2 + 1] = (v2f){-cc.z * qc, -cc.w * qd};
    }
    const v2f negl2 = {NEGL, NEGL};

    const int rowEnd = (row0 + ROWS_PER_WAVE < N) ? (row0 + ROWS_PER_WAVE) : N;
    for (int n = row0; n < rowEnd; ++n) {
        const float4* __restrict__ xr =
            reinterpret_cast<const float4*>(X + (size_t)n * DDIM);

        v2f acc[4] = {{0.f, 0.f}, {0.f, 0.f}, {0.f, 0.f}, {0.f, 0.f}};
        // Two halves of 16 floats each: keeps live X registers at 16 (not 32).
        #pragma unroll
        for (int h = 0; h < 2; ++h) {
            float4 x0 = xr[4 * h + 0];
            float4 x1 = xr[4 * h + 1];
            float4 x2 = xr[4 * h + 2];
            float4 x3 = xr[4 * h + 3];
            v2f xs[8] = {
                {x0.x, x0.y}, {x0.z, x0.w}, {x1.x, x1.y}, {x1.z, x1.w},
                {x2.x, x2.y}, {x2.z, x2.w}, {x3.x, x3.y}, {x3.z, x3.w}};
            #pragma unroll
            for (int p = 0; p < 8; ++p) {
                const int dp = h * 8 + p;
                v2f t = __builtin_elementwise_fma(q2[dp], xs[p], pn2[dp]);
                v2f u = t * t;
                v2f w = __builtin_elementwise_min(u, negl2);
                acc[p & 3] += w;
            }
        }
        v2f av = (acc[0] + acc[1]) + (acc[2] + acc[3]);
        float a = -(av.x + av.y);
        float mem = fast_exp2(a);

        // Wave-wide sum across the 64 rules.
        float S = mem;
        #pragma unroll
        for (int k = 32; k >= 1; k >>= 1)
            S += __shfl_xor(S, k, 64);

        out[(size_t)n * RR + lane] = mem * __builtin_amdgcn_rcpf(S + 1e-8f);
    }
}

extern "C" void kernel_launch(void* const* d_in, const int* in_sizes, int n_in,
                              void* d_out, int out_size, void* d_ws, size_t ws_size,
                              hipStream_t stream) {
    const float* X       = (const float*)d_in[0];
    const float* centers = (const float*)d_in[1];
    const float* sigma   = (const float*)d_in[2];
    float* out = (float*)d_out;

    const int N = in_sizes[0] / DDIM;  // 100000
    const int nwaves = (N + ROWS_PER_WAVE - 1) / ROWS_PER_WAVE;
    const int grid = (nwaves + WPB - 1) / WPB;

    gauss_antecedent_kernel<<<grid, 256, 0, stream>>>(X, centers, sigma, out, N);
}